// Round 3
// baseline (449.671 us; speedup 1.0000x reference)
//
#include <hip/hip_runtime.h>
#include <math.h>

#define B_     4
#define N_     2048
#define F_     256
#define H_     4
#define DH     64
#define CHUNK_ 256
#define NC     8
#define BN     8192

// ---------------------------------------------------------------------------
// Kernel 1: QKV projections.  out = x @ W^T + b, written as [b][h][n][dh].
// 64x64 output tile per block, 256 threads (16x16), 4x4 register microtile,
// K-step 16 with transposed LDS staging so both operands read as float4.
// ---------------------------------------------------------------------------
__global__ __launch_bounds__(256) void proj_kernel(
    const float* __restrict__ x,
    const float* __restrict__ Wq, const float* __restrict__ bq,
    const float* __restrict__ Wk, const float* __restrict__ bk,
    const float* __restrict__ Wv, const float* __restrict__ bv,
    float* __restrict__ Q, float* __restrict__ K, float* __restrict__ V)
{
    const int which = blockIdx.z;
    const float* W    = (which == 0) ? Wq : (which == 1) ? Wk : Wv;
    const float* bias = (which == 0) ? bq : (which == 1) ? bk : bv;
    float* dst        = (which == 0) ? Q  : (which == 1) ? K  : V;

    const int r0 = blockIdx.x * 64;   // row tile within BN
    const int c0 = blockIdx.y * 64;   // col tile within F (c0 = h*64)
    const int tx = threadIdx.x, ty = threadIdx.y;
    const int tid = ty * 16 + tx;

    __shared__ float xs[16][68];   // [k][row], transposed   (64 rows x 16 k)
    __shared__ float wsh[16][68];  // [k][col], transposed

    float acc[4][4];
#pragma unroll
    for (int i = 0; i < 4; i++)
#pragma unroll
        for (int j = 0; j < 4; j++) acc[i][j] = 0.f;

    const int lrow = tid >> 2;   // 0..63
    const int lc4  = tid & 3;    // 0..3   (k-offset group: 16 k total)

    for (int k0 = 0; k0 < F_; k0 += 16) {
        // 64 rows x 16 k = 1024 floats = 256 threads x float4  (exact)
        float4 xa = *(const float4*)(x + (size_t)(r0 + lrow) * F_ + k0 + lc4 * 4);
        float4 wa = *(const float4*)(W + (size_t)(c0 + lrow) * F_ + k0 + lc4 * 4);
        __syncthreads();
        xs[lc4 * 4 + 0][lrow] = xa.x; xs[lc4 * 4 + 1][lrow] = xa.y;
        xs[lc4 * 4 + 2][lrow] = xa.z; xs[lc4 * 4 + 3][lrow] = xa.w;
        wsh[lc4 * 4 + 0][lrow] = wa.x; wsh[lc4 * 4 + 1][lrow] = wa.y;
        wsh[lc4 * 4 + 2][lrow] = wa.z; wsh[lc4 * 4 + 3][lrow] = wa.w;
        __syncthreads();
#pragma unroll
        for (int kk = 0; kk < 16; kk++) {
            float4 a4 = *(const float4*)&xs[kk][ty * 4];
            float4 w4 = *(const float4*)&wsh[kk][tx * 4];
            float av[4] = {a4.x, a4.y, a4.z, a4.w};
            float wv[4] = {w4.x, w4.y, w4.z, w4.w};
#pragma unroll
            for (int i = 0; i < 4; i++)
#pragma unroll
                for (int j = 0; j < 4; j++)
                    acc[i][j] += av[i] * wv[j];
        }
    }

    const int hsel = c0 >> 6;   // head index (c0 is a multiple of 64)
#pragma unroll
    for (int i = 0; i < 4; i++) {
        const int row = r0 + ty * 4 + i;
        const int bb  = row >> 11;        // / N_
        const int nn  = row & (N_ - 1);
        float4 o4;
        o4.x = acc[i][0] + bias[c0 + tx * 4 + 0];
        o4.y = acc[i][1] + bias[c0 + tx * 4 + 1];
        o4.z = acc[i][2] + bias[c0 + tx * 4 + 2];
        o4.w = acc[i][3] + bias[c0 + tx * 4 + 3];
        *(float4*)(dst + ((size_t)(bb * H_ + hsel) * N_ + nn) * DH + tx * 4) = o4;
    }
}

// ---------------------------------------------------------------------------
// Kernel 2: chunked attention.  One block = 64 queries of one (b,h).
// Tiles are 64x64 = 4096 floats -> each thread stages FOUR float4s (the
// round-1 bug staged only one).  Per 64-key tile: S = (Q·K^T)/8, clip, mask,
// exp -> pt (LDS), rowsum via shuffles; PV accumulates the unnormalized chunk
// context; at chunk end divide by the per-chunk softmax denominator.
// ---------------------------------------------------------------------------
__global__ __launch_bounds__(256) void attn_kernel(
    const float* __restrict__ Qp, const float* __restrict__ Kp,
    const float* __restrict__ Vp, const int* __restrict__ adj,
    float* __restrict__ CTX)
{
    const int qb = blockIdx.x * 64;
    const int h  = blockIdx.y;
    const int b  = blockIdx.z;
    const int bh = b * H_ + h;
    const int tx = threadIdx.x, ty = threadIdx.y;
    const int tid = ty * 16 + tx;

    __shared__ float qs[64][68];  // [d][q] (transposed Q tile)
    __shared__ float kv[64][68];  // K phase: [d][k]; V phase: [k][d]
    __shared__ float pt[64][68];  // [k][q] exp'd scores

    const int srow = tid >> 4;        // 0..15
    const int scol = (tid & 15) * 4;  // 0,4,...,60

    // ---- stage Q transposed: full 64x64 tile, 4 float4 per thread ----
#pragma unroll
    for (int r = 0; r < 4; r++) {
        const int row = srow + r * 16;   // query within tile
        float4 qa = *(const float4*)(Qp + ((size_t)bh * N_ + qb + row) * DH + scol);
        qs[scol + 0][row] = qa.x; qs[scol + 1][row] = qa.y;
        qs[scol + 2][row] = qa.z; qs[scol + 3][row] = qa.w;
    }

    float ctx_tot[4][4];
#pragma unroll
    for (int i = 0; i < 4; i++)
#pragma unroll
        for (int j = 0; j < 4; j++) ctx_tot[i][j] = 0.f;

    for (int c = 0; c < NC; c++) {
        float ctx_ch[4][4];
        float rs[4] = {0.f, 0.f, 0.f, 0.f};
#pragma unroll
        for (int i = 0; i < 4; i++)
#pragma unroll
            for (int j = 0; j < 4; j++) ctx_ch[i][j] = 0.f;

        for (int kt = 0; kt < 4; kt++) {
            const int k0 = c * CHUNK_ + kt * 64;

            // prefetch the full 64x64 K and V tiles (4 float4 each)
            float4 ka[4], va[4];
#pragma unroll
            for (int r = 0; r < 4; r++) {
                const int row = srow + r * 16;   // key within tile
                ka[r] = *(const float4*)(Kp + ((size_t)bh * N_ + k0 + row) * DH + scol);
                va[r] = *(const float4*)(Vp + ((size_t)bh * N_ + k0 + row) * DH + scol);
            }

            __syncthreads();  // prev tile's kv/pt consumers done
#pragma unroll
            for (int r = 0; r < 4; r++) {
                const int row = srow + r * 16;
                kv[scol + 0][row] = ka[r].x; kv[scol + 1][row] = ka[r].y;
                kv[scol + 2][row] = ka[r].z; kv[scol + 3][row] = ka[r].w;
            }
            __syncthreads();

            // ---- S = Q · K^T (64q x 64k), 4x4 per thread ----
            float s[4][4];
#pragma unroll
            for (int i = 0; i < 4; i++)
#pragma unroll
                for (int j = 0; j < 4; j++) s[i][j] = 0.f;
#pragma unroll 4
            for (int d = 0; d < DH; d++) {
                float4 a4 = *(const float4*)&qs[d][ty * 4];
                float4 k4 = *(const float4*)&kv[d][tx * 4];
                float av[4] = {a4.x, a4.y, a4.z, a4.w};
                float kvv[4] = {k4.x, k4.y, k4.z, k4.w};
#pragma unroll
                for (int i = 0; i < 4; i++)
#pragma unroll
                    for (int j = 0; j < 4; j++)
                        s[i][j] += av[i] * kvv[j];
            }

            // ---- scale, clip, mask, exp; write pt; partial rowsums ----
            float part[4];
#pragma unroll
            for (int i = 0; i < 4; i++) {
                const int qg = qb + ty * 4 + i;
                const int4 m = *(const int4*)(adj + (size_t)qg * N_ + k0 + tx * 4);
                const int mm[4] = {m.x, m.y, m.z, m.w};
                float e[4];
#pragma unroll
                for (int j = 0; j < 4; j++) {
                    float sv = s[i][j] * 0.125f;
                    sv = fminf(fmaxf(sv, -10.f), 10.f);
                    if (mm[j] == 0) sv = -10.f;
                    e[j] = __expf(sv);
                    pt[tx * 4 + j][ty * 4 + i] = e[j];
                }
                part[i] = (e[0] + e[1]) + (e[2] + e[3]);
            }
            // reduce over the 16 tx-lanes (xor bits 0..3 stay within ty row)
#pragma unroll
            for (int i = 0; i < 4; i++) {
                float p = part[i];
                p += __shfl_xor(p, 1);
                p += __shfl_xor(p, 2);
                p += __shfl_xor(p, 4);
                p += __shfl_xor(p, 8);
                rs[i] += p;
            }

            __syncthreads();  // kv(K) reads + pt writes complete
#pragma unroll
            for (int r = 0; r < 4; r++) {
                const int row = srow + r * 16;
                *(float4*)&kv[row][scol] = va[r];   // V tile, direct [k][d]
            }
            __syncthreads();

            // ---- ctx_ch += P~ · V  (unnormalized) ----
#pragma unroll 4
            for (int k = 0; k < 64; k++) {
                float4 p4 = *(const float4*)&pt[k][ty * 4];
                float4 v4 = *(const float4*)&kv[k][tx * 4];
                float pv[4] = {p4.x, p4.y, p4.z, p4.w};
                float vv[4] = {v4.x, v4.y, v4.z, v4.w};
#pragma unroll
                for (int i = 0; i < 4; i++)
#pragma unroll
                    for (int j = 0; j < 4; j++)
                        ctx_ch[i][j] += pv[i] * vv[j];
            }
        }

        // per-chunk softmax normalization, accumulate into total
#pragma unroll
        for (int i = 0; i < 4; i++) {
            const float inv = 1.0f / rs[i];
#pragma unroll
            for (int j = 0; j < 4; j++)
                ctx_tot[i][j] += ctx_ch[i][j] * inv;
        }
    }

    // write CTX as [b][n][F] (n-major, ready for the output GEMM)
#pragma unroll
    for (int i = 0; i < 4; i++) {
        const int n = qb + ty * 4 + i;
        float4 o4;
        o4.x = ctx_tot[i][0]; o4.y = ctx_tot[i][1];
        o4.z = ctx_tot[i][2]; o4.w = ctx_tot[i][3];
        *(float4*)(CTX + ((size_t)b * N_ + n) * F_ + h * DH + tx * 4) = o4;
    }
}

// ---------------------------------------------------------------------------
// Kernel 3a: transpose Wo (256x256) so the epilogue GEMM reads coalesced.
// ---------------------------------------------------------------------------
__global__ __launch_bounds__(256) void transpose_wo(
    const float* __restrict__ Wo, float* __restrict__ WoT)
{
    const int idx = blockIdx.x * 256 + threadIdx.x;
    const int f = idx >> 8;
    const int o = idx & 255;
    WoT[(size_t)f * F_ + o] = Wo[(size_t)o * F_ + f];
}

// ---------------------------------------------------------------------------
// Kernel 3b: out = LN(ctx @ Wo^T + bo + x).  Block = 4 rows x 256 cols.
// ---------------------------------------------------------------------------
__global__ __launch_bounds__(256) void out_ln_kernel(
    const float* __restrict__ CTX, const float* __restrict__ x,
    const float* __restrict__ WoT, const float* __restrict__ bo,
    const float* __restrict__ gamma, const float* __restrict__ beta,
    float* __restrict__ out)
{
    const int n0 = blockIdx.x * 4;
    const int o  = threadIdx.x;

    float acc[4] = {0.f, 0.f, 0.f, 0.f};
    for (int f = 0; f < F_; f += 4) {
        const float w0 = WoT[(size_t)(f + 0) * F_ + o];
        const float w1 = WoT[(size_t)(f + 1) * F_ + o];
        const float w2 = WoT[(size_t)(f + 2) * F_ + o];
        const float w3 = WoT[(size_t)(f + 3) * F_ + o];
#pragma unroll
        for (int r = 0; r < 4; r++) {
            float4 c4 = *(const float4*)(CTX + (size_t)(n0 + r) * F_ + f);
            acc[r] += c4.x * w0 + c4.y * w1 + c4.z * w2 + c4.w * w3;
        }
    }

    float ov[4];
#pragma unroll
    for (int r = 0; r < 4; r++)
        ov[r] = acc[r] + bo[o] + x[(size_t)(n0 + r) * F_ + o];

    __shared__ float psum[4][4], psq[4][4];
    const int wave = o >> 6, lane = o & 63;
#pragma unroll
    for (int r = 0; r < 4; r++) {
        float sv = ov[r], qv = ov[r] * ov[r];
#pragma unroll
        for (int off = 1; off < 64; off <<= 1) {
            sv += __shfl_xor(sv, off);
            qv += __shfl_xor(qv, off);
        }
        if (lane == 0) { psum[wave][r] = sv; psq[wave][r] = qv; }
    }
    __syncthreads();
#pragma unroll
    for (int r = 0; r < 4; r++) {
        const float S  = (psum[0][r] + psum[1][r]) + (psum[2][r] + psum[3][r]);
        const float Q2 = (psq[0][r] + psq[1][r]) + (psq[2][r] + psq[3][r]);
        const float mu  = S * (1.0f / F_);
        const float var = Q2 * (1.0f / F_) - mu * mu;
        const float inv = rsqrtf(var + 1e-5f);
        out[(size_t)(n0 + r) * F_ + o] = (ov[r] - mu) * inv * gamma[o] + beta[o];
    }
}

// ---------------------------------------------------------------------------
extern "C" void kernel_launch(void* const* d_in, const int* in_sizes, int n_in,
                              void* d_out, int out_size, void* d_ws, size_t ws_size,
                              hipStream_t stream)
{
    const float* x     = (const float*)d_in[0];
    const int*   adj   = (const int*)  d_in[1];
    const float* Wq    = (const float*)d_in[2];
    const float* bq    = (const float*)d_in[3];
    const float* Wk    = (const float*)d_in[4];
    const float* bk    = (const float*)d_in[5];
    const float* Wv    = (const float*)d_in[6];
    const float* bv    = (const float*)d_in[7];
    const float* Wo    = (const float*)d_in[8];
    const float* bo    = (const float*)d_in[9];
    const float* gamma = (const float*)d_in[10];
    const float* beta  = (const float*)d_in[11];
    float* out = (float*)d_out;

    float* ws = (float*)d_ws;
    const size_t SZ = (size_t)BN * F_;       // 2,097,152 floats per tensor
    float* Q   = ws;
    float* K   = ws + SZ;
    float* V   = ws + 2 * SZ;
    float* CTX = ws + 3 * SZ;
    float* WoT = ws + 4 * SZ;                // + 65,536 floats

    dim3 blk2(16, 16);
    hipLaunchKernelGGL(proj_kernel, dim3(BN / 64, F_ / 64, 3), blk2, 0, stream,
                       x, Wq, bq, Wk, bk, Wv, bv, Q, K, V);
    hipLaunchKernelGGL(transpose_wo, dim3((F_ * F_) / 256), dim3(256), 0, stream,
                       Wo, WoT);
    hipLaunchKernelGGL(attn_kernel, dim3(N_ / 64, H_, B_), blk2, 0, stream,
                       Q, K, V, adj, CTX);
    hipLaunchKernelGGL(out_ln_kernel, dim3(BN / 4), dim3(256), 0, stream,
                       CTX, x, WoT, bo, gamma, beta, out);
}

// Round 4
// 206.076 us; speedup vs baseline: 2.1821x; 2.1821x over previous
//
#include <hip/hip_runtime.h>
#include <math.h>

#define B_     4
#define N_     2048
#define F_     256
#define H_     4
#define DH     64
#define NC     8
#define BN     8192
#define SP     72   // padded f16 row stride (64 + 8) -> 144 B, 16B-aligned, 2-way max

typedef _Float16 f16;
typedef _Float16 half8  __attribute__((ext_vector_type(8)));
typedef _Float16 half4v __attribute__((ext_vector_type(4)));
typedef float    floatx4 __attribute__((ext_vector_type(4)));

// ---------------------------------------------------------------------------
// Kernel 0: fp32 -> f16 convert for x, Wq, Wk, Wv.
// ---------------------------------------------------------------------------
__global__ __launch_bounds__(256) void convert_f16(
    const float* __restrict__ x,  const float* __restrict__ Wq,
    const float* __restrict__ Wk, const float* __restrict__ Wv,
    f16* __restrict__ xh, f16* __restrict__ Wqh,
    f16* __restrict__ Wkh, f16* __restrict__ Wvh)
{
    const int bid = blockIdx.x;
    const float* src; f16* dst; int base;
    if (bid < 2048)      { src = x;  dst = xh;  base = bid * 1024; }
    else if (bid < 2112) { src = Wq; dst = Wqh; base = (bid - 2048) * 1024; }
    else if (bid < 2176) { src = Wk; dst = Wkh; base = (bid - 2112) * 1024; }
    else                 { src = Wv; dst = Wvh; base = (bid - 2176) * 1024; }
    const int idx = base + threadIdx.x * 4;
    float4 v = *(const float4*)(src + idx);
    half4v h; h[0] = (f16)v.x; h[1] = (f16)v.y; h[2] = (f16)v.z; h[3] = (f16)v.w;
    *(half4v*)(dst + idx) = h;
}

// ---------------------------------------------------------------------------
// Kernel 1: QKV projection via MFMA.  D = x @ W^T (+bias), f16 in/out, fp32 acc.
// Block: 256 thr (4 waves); 64 n x 64 o tile; wave owns 16 n x 64 o.
// A = x[n][f] natural rows; B = W[o][f] natural rows (B[k=f][n=o]).
// Output staged through LDS for vectorized f16 global stores, [b][h][n][dh].
// ---------------------------------------------------------------------------
__global__ __launch_bounds__(256) void proj_mfma(
    const f16* __restrict__ xh,
    const f16* __restrict__ Wqh, const f16* __restrict__ Wkh, const f16* __restrict__ Wvh,
    const float* __restrict__ bq, const float* __restrict__ bk, const float* __restrict__ bv,
    f16* __restrict__ Qh, f16* __restrict__ Kh, f16* __restrict__ Vh)
{
    const int which = blockIdx.z;
    const f16*   W    = which == 0 ? Wqh : which == 1 ? Wkh : Wvh;
    const float* bias = which == 0 ? bq  : which == 1 ? bk  : bv;
    f16*         dst  = which == 0 ? Qh  : which == 1 ? Kh  : Vh;

    const int r0 = blockIdx.x * 64;
    const int hy = blockIdx.y;
    const int c0 = hy * 64;
    const int tid  = threadIdx.x;
    const int wave = tid >> 6, lane = tid & 63;
    const int quad = lane >> 4, l16 = lane & 15;
    const int row = tid >> 2, seg = tid & 3;

    __shared__ f16 xs[64 * SP];
    __shared__ f16 wsm[64 * SP];

    floatx4 zz = {0.f, 0.f, 0.f, 0.f};
    floatx4 acc[4] = {zz, zz, zz, zz};

    for (int f0 = 0; f0 < F_; f0 += 64) {
        const f16* xsrc = xh + (size_t)(r0 + row) * F_ + f0 + seg * 16;
        const f16* wsrc = W  + (size_t)(c0 + row) * F_ + f0 + seg * 16;
        float4 xa0 = *(const float4*)(xsrc), xa1 = *(const float4*)(xsrc + 8);
        float4 wa0 = *(const float4*)(wsrc), wa1 = *(const float4*)(wsrc + 8);
        __syncthreads();
        *(float4*)&xs[row * SP + seg * 16]      = xa0;
        *(float4*)&xs[row * SP + seg * 16 + 8]  = xa1;
        *(float4*)&wsm[row * SP + seg * 16]     = wa0;
        *(float4*)&wsm[row * SP + seg * 16 + 8] = wa1;
        __syncthreads();
#pragma unroll
        for (int s = 0; s < 2; s++) {
            half8 af = *(const half8*)&xs[(wave * 16 + l16) * SP + s * 32 + quad * 8];
#pragma unroll
            for (int ot = 0; ot < 4; ot++) {
                half8 bf = *(const half8*)&wsm[(ot * 16 + l16) * SP + s * 32 + quad * 8];
                acc[ot] = __builtin_amdgcn_mfma_f32_16x16x32_f16(af, bf, acc[ot], 0, 0, 0);
            }
        }
    }

    __syncthreads();
    f16* outb = xs;   // reuse
#pragma unroll
    for (int ot = 0; ot < 4; ot++) {
        const float bv_ = bias[c0 + ot * 16 + l16];
#pragma unroll
        for (int r = 0; r < 4; r++)
            outb[(wave * 16 + quad * 4 + r) * SP + ot * 16 + l16] = (f16)(acc[ot][r] + bv_);
    }
    __syncthreads();

    const int gr = r0 + row;
    const int bb = gr >> 11, nn = gr & (N_ - 1);
    f16* gdst = dst + (((size_t)bb * H_ + hy) * N_ + nn) * DH + seg * 16;
    *(float4*)(gdst)     = *(const float4*)&outb[row * SP + seg * 16];
    *(float4*)(gdst + 8) = *(const float4*)&outb[row * SP + seg * 16 + 8];
}

// ---------------------------------------------------------------------------
// Kernel 2: V [bh][n][dh] -> Vt [bh][dh][n]  (f16), 64x64 tiles via LDS.
// ---------------------------------------------------------------------------
__global__ __launch_bounds__(256) void transpose_v(
    const f16* __restrict__ Vh, f16* __restrict__ Vt)
{
    const int n0 = blockIdx.x * 64;
    const int bh = blockIdx.y;
    const int tid = threadIdx.x;
    const int row = tid >> 2, seg = tid & 3;
    __shared__ f16 tile[64 * SP];

    const f16* src = Vh + ((size_t)bh * N_ + n0 + row) * DH + seg * 16;
    *(float4*)&tile[row * SP + seg * 16]     = *(const float4*)(src);
    *(float4*)&tile[row * SP + seg * 16 + 8] = *(const float4*)(src + 8);
    __syncthreads();

    const int d = tid >> 2, ch = tid & 3;
    f16 tmp[16];
#pragma unroll
    for (int i = 0; i < 16; i++) tmp[i] = tile[(ch * 16 + i) * SP + d];
    f16* gdst = Vt + ((size_t)bh * DH + d) * N_ + n0 + ch * 16;
    *(float4*)(gdst)     = *(const float4*)&tmp[0];
    *(float4*)(gdst + 8) = *(const float4*)&tmp[8];
}

// ---------------------------------------------------------------------------
// Kernel 3: MFMA chunked attention.  Block = 64 q of one (b,h); 4 waves,
// wave owns 16 q.  S^T = K·Q^T (C col=q!), clip/mask/exp in C-regs, rowsum
// via 2 shuffles, P^T -> wave-private LDS, ctx^T = V^T·P^T, per-chunk
// normalize with lane-uniform 1/rs, fp32 CTX out.
// ---------------------------------------------------------------------------
__global__ __launch_bounds__(256) void attn_mfma(
    const f16* __restrict__ Qh, const f16* __restrict__ Kh,
    const f16* __restrict__ Vt, const int* __restrict__ adj,
    float* __restrict__ CTX)
{
    const int qb = blockIdx.x * 64;
    const int h  = blockIdx.y;
    const int b  = blockIdx.z;
    const int bh = b * H_ + h;
    const int tid  = threadIdx.x;
    const int wave = tid >> 6, lane = tid & 63;
    const int quad = lane >> 4, l16 = lane & 15;
    const int row = tid >> 2, seg = tid & 3;

    __shared__ f16 Qs[64 * SP];
    __shared__ f16 Ks[64 * SP];
    __shared__ f16 Vs[64 * SP];          // [d][key]
    __shared__ f16 Ps[4 * 16 * SP];      // per-wave [16 q][64 key]

    {   // stage Q tile [q][dh]
        const f16* src = Qh + ((size_t)bh * N_ + qb + row) * DH + seg * 16;
        *(float4*)&Qs[row * SP + seg * 16]     = *(const float4*)(src);
        *(float4*)&Qs[row * SP + seg * 16 + 8] = *(const float4*)(src + 8);
    }
    __syncthreads();
    // Q B-fragments live in registers for the whole kernel
    const half8 qf0 = *(const half8*)&Qs[(wave * 16 + l16) * SP + quad * 8];
    const half8 qf1 = *(const half8*)&Qs[(wave * 16 + l16) * SP + 32 + quad * 8];

    const int qglob = qb + wave * 16 + l16;
    const int* adjrow = adj + (size_t)qglob * N_;

    floatx4 zz = {0.f, 0.f, 0.f, 0.f};
    floatx4 ctx_tot[4] = {zz, zz, zz, zz};

    for (int c = 0; c < NC; c++) {
        floatx4 ctx_ch[4] = {zz, zz, zz, zz};
        float rs_ch = 0.f;

        for (int kt = 0; kt < 4; kt++) {
            const int k0 = c * 256 + kt * 64;
            // prefetch K tile [key][dh] and V^T tile [d][key]
            const f16* ksrc = Kh + ((size_t)bh * N_ + k0 + row) * DH + seg * 16;
            const f16* vsrc = Vt + ((size_t)bh * DH + row) * N_ + k0 + seg * 16;
            float4 ka0 = *(const float4*)(ksrc), ka1 = *(const float4*)(ksrc + 8);
            float4 va0 = *(const float4*)(vsrc), va1 = *(const float4*)(vsrc + 8);
            __syncthreads();
            *(float4*)&Ks[row * SP + seg * 16]     = ka0;
            *(float4*)&Ks[row * SP + seg * 16 + 8] = ka1;
            *(float4*)&Vs[row * SP + seg * 16]     = va0;
            *(float4*)&Vs[row * SP + seg * 16 + 8] = va1;
            __syncthreads();

            float rs = 0.f;
#pragma unroll
            for (int m = 0; m < 4; m++) {
                floatx4 sacc = zz;
                half8 a0 = *(const half8*)&Ks[(m * 16 + l16) * SP + quad * 8];
                half8 a1 = *(const half8*)&Ks[(m * 16 + l16) * SP + 32 + quad * 8];
                sacc = __builtin_amdgcn_mfma_f32_16x16x32_f16(a0, qf0, sacc, 0, 0, 0);
                sacc = __builtin_amdgcn_mfma_f32_16x16x32_f16(a1, qf1, sacc, 0, 0, 0);
                // mask+clip+exp; C layout: col=q (lane-fixed), row=key=quad*4+reg
                const int4 mm = *(const int4*)(adjrow + k0 + m * 16 + quad * 4);
                const int mv[4] = {mm.x, mm.y, mm.z, mm.w};
                half4v pv;
#pragma unroll
                for (int r = 0; r < 4; r++) {
                    float sv = sacc[r] * 0.125f;
                    sv = fminf(fmaxf(sv, -10.f), 10.f);
                    sv = (mv[r] == 0) ? -10.f : sv;
                    const float ev = __expf(sv);
                    rs += ev;
                    pv[r] = (f16)ev;
                }
                *(half4v*)&Ps[(wave * 16 + l16) * SP + m * 16 + quad * 4] = pv;
            }
            // full 64-key rowsum for this lane's q (sum across quads)
            rs += __shfl_xor(rs, 16);
            rs += __shfl_xor(rs, 32);
            rs_ch += rs;

            // ctx^T += V^T · P^T   (P is wave-private: no barrier needed)
            const half8 p0 = *(const half8*)&Ps[(wave * 16 + l16) * SP + quad * 8];
            const half8 p1 = *(const half8*)&Ps[(wave * 16 + l16) * SP + 32 + quad * 8];
#pragma unroll
            for (int m = 0; m < 4; m++) {
                half8 va = *(const half8*)&Vs[(m * 16 + l16) * SP + quad * 8];
                half8 vb = *(const half8*)&Vs[(m * 16 + l16) * SP + 32 + quad * 8];
                ctx_ch[m] = __builtin_amdgcn_mfma_f32_16x16x32_f16(va, p0, ctx_ch[m], 0, 0, 0);
                ctx_ch[m] = __builtin_amdgcn_mfma_f32_16x16x32_f16(vb, p1, ctx_ch[m], 0, 0, 0);
            }
        }

        const float inv = 1.0f / rs_ch;   // lane-uniform in q across all 16 regs
#pragma unroll
        for (int m = 0; m < 4; m++)
#pragma unroll
            for (int r = 0; r < 4; r++)
                ctx_tot[m][r] += ctx_ch[m][r] * inv;
    }

    // store: col=q (lane-fixed), rows d = m*16 + quad*4 + r  -> contiguous float4
#pragma unroll
    for (int m = 0; m < 4; m++) {
        float4 o;
        o.x = ctx_tot[m][0]; o.y = ctx_tot[m][1];
        o.z = ctx_tot[m][2]; o.w = ctx_tot[m][3];
        *(float4*)&CTX[((size_t)b * N_ + qglob) * F_ + h * DH + m * 16 + quad * 4] = o;
    }
}

// ---------------------------------------------------------------------------
// Kernel 4a: transpose Wo (256x256 fp32) for the coalesced epilogue.
// ---------------------------------------------------------------------------
__global__ __launch_bounds__(256) void transpose_wo(
    const float* __restrict__ Wo, float* __restrict__ WoT)
{
    const int idx = blockIdx.x * 256 + threadIdx.x;
    const int f = idx >> 8;
    const int o = idx & 255;
    WoT[(size_t)f * F_ + o] = Wo[(size_t)o * F_ + f];
}

// ---------------------------------------------------------------------------
// Kernel 4b: out = LN(ctx @ Wo^T + bo + x), fp32.  Block = 4 rows x 256 cols.
// ---------------------------------------------------------------------------
__global__ __launch_bounds__(256) void out_ln_kernel(
    const float* __restrict__ CTX, const float* __restrict__ x,
    const float* __restrict__ WoT, const float* __restrict__ bo,
    const float* __restrict__ gamma, const float* __restrict__ beta,
    float* __restrict__ out)
{
    const int n0 = blockIdx.x * 4;
    const int o  = threadIdx.x;

    float acc[4] = {0.f, 0.f, 0.f, 0.f};
    for (int f = 0; f < F_; f += 4) {
        const float w0 = WoT[(size_t)(f + 0) * F_ + o];
        const float w1 = WoT[(size_t)(f + 1) * F_ + o];
        const float w2 = WoT[(size_t)(f + 2) * F_ + o];
        const float w3 = WoT[(size_t)(f + 3) * F_ + o];
#pragma unroll
        for (int r = 0; r < 4; r++) {
            float4 c4 = *(const float4*)(CTX + (size_t)(n0 + r) * F_ + f);
            acc[r] += c4.x * w0 + c4.y * w1 + c4.z * w2 + c4.w * w3;
        }
    }

    float ov[4];
#pragma unroll
    for (int r = 0; r < 4; r++)
        ov[r] = acc[r] + bo[o] + x[(size_t)(n0 + r) * F_ + o];

    __shared__ float psum[4][4], psq[4][4];
    const int wave = o >> 6, lane = o & 63;
#pragma unroll
    for (int r = 0; r < 4; r++) {
        float sv = ov[r], qv = ov[r] * ov[r];
#pragma unroll
        for (int off = 1; off < 64; off <<= 1) {
            sv += __shfl_xor(sv, off);
            qv += __shfl_xor(qv, off);
        }
        if (lane == 0) { psum[wave][r] = sv; psq[wave][r] = qv; }
    }
    __syncthreads();
#pragma unroll
    for (int r = 0; r < 4; r++) {
        const float S  = (psum[0][r] + psum[1][r]) + (psum[2][r] + psum[3][r]);
        const float Q2 = (psq[0][r] + psq[1][r]) + (psq[2][r] + psq[3][r]);
        const float mu  = S * (1.0f / F_);
        const float var = Q2 * (1.0f / F_) - mu * mu;
        const float inv = rsqrtf(var + 1e-5f);
        out[(size_t)(n0 + r) * F_ + o] = (ov[r] - mu) * inv * gamma[o] + beta[o];
    }
}

// ---------------------------------------------------------------------------
extern "C" void kernel_launch(void* const* d_in, const int* in_sizes, int n_in,
                              void* d_out, int out_size, void* d_ws, size_t ws_size,
                              hipStream_t stream)
{
    const float* x     = (const float*)d_in[0];
    const int*   adj   = (const int*)  d_in[1];
    const float* Wq    = (const float*)d_in[2];
    const float* bq    = (const float*)d_in[3];
    const float* Wk    = (const float*)d_in[4];
    const float* bk    = (const float*)d_in[5];
    const float* Wv    = (const float*)d_in[6];
    const float* bv    = (const float*)d_in[7];
    const float* Wo    = (const float*)d_in[8];
    const float* bo    = (const float*)d_in[9];
    const float* gamma = (const float*)d_in[10];
    const float* beta  = (const float*)d_in[11];
    float* out = (float*)d_out;

    float* ws = (float*)d_ws;
    // fp32 regions
    float* CTX = ws;                        // 2,097,152 floats
    float* WoT = ws + 2097152;              //    65,536 floats
    // f16 regions (sizes in floats: halves/2)
    f16* xh  = (f16*)(ws + 2162688);        // 2M halves
    f16* Wqh = (f16*)(ws + 3211264);        // 64K halves
    f16* Wkh = (f16*)(ws + 3244032);
    f16* Wvh = (f16*)(ws + 3276800);
    f16* Qh  = (f16*)(ws + 3309568);        // 2M halves, [bh][n][dh]
    f16* Kh  = (f16*)(ws + 4358144);
    f16* Vh  = (f16*)(ws + 5406720);
    f16* Vt  = (f16*)(ws + 6455296);        // [bh][dh][n]

    hipLaunchKernelGGL(convert_f16, dim3(2240), dim3(256), 0, stream,
                       x, Wq, Wk, Wv, xh, Wqh, Wkh, Wvh);
    hipLaunchKernelGGL(proj_mfma, dim3(BN / 64, H_, 3), dim3(256), 0, stream,
                       xh, Wqh, Wkh, Wvh, bq, bk, bv, Qh, Kh, Vh);
    hipLaunchKernelGGL(transpose_v, dim3(N_ / 64, B_ * H_), dim3(256), 0, stream,
                       Vh, Vt);
    hipLaunchKernelGGL(transpose_wo, dim3((F_ * F_) / 256), dim3(256), 0, stream,
                       Wo, WoT);
    hipLaunchKernelGGL(attn_mfma, dim3(N_ / 64, H_, B_), dim3(256), 0, stream,
                       Qh, Kh, Vt, adj, CTX);
    hipLaunchKernelGGL(out_ln_kernel, dim3(BN / 4), dim3(256), 0, stream,
                       CTX, x, WoT, bo, gamma, beta, out);
}

// Round 5
// 186.753 us; speedup vs baseline: 2.4078x; 1.1035x over previous
//
#include <hip/hip_runtime.h>
#include <math.h>

#define B_     4
#define N_     2048
#define F_     256
#define H_     4
#define DH     64
#define NC     8
#define BN     8192
#define SP     72   // padded f16 row stride (64 + 8) -> 144 B, 16B-aligned

typedef _Float16 f16;
typedef _Float16 half8  __attribute__((ext_vector_type(8)));
typedef _Float16 half4v __attribute__((ext_vector_type(4)));
typedef float    floatx4 __attribute__((ext_vector_type(4)));
typedef unsigned long long u64;

__device__ __forceinline__ half8 cvt8(float4 a, float4 b) {
    half8 h;
    h[0] = (f16)a.x; h[1] = (f16)a.y; h[2] = (f16)a.z; h[3] = (f16)a.w;
    h[4] = (f16)b.x; h[5] = (f16)b.y; h[6] = (f16)b.z; h[7] = (f16)b.w;
    return h;
}

// ---------------------------------------------------------------------------
// Kernel 0: pack adj into 1 bit/key: P[row][w] (w = key>>6), bit i = key w*64+i.
// ---------------------------------------------------------------------------
__global__ __launch_bounds__(256) void pack_adj(
    const int* __restrict__ adj, u64* __restrict__ P)
{
    const int row   = blockIdx.x >> 3;
    const int chunk = blockIdx.x & 7;
    const int wave  = threadIdx.x >> 6, lane = threadIdx.x & 63;
    const int key   = chunk * 256 + wave * 64 + lane;
    u64 m = __ballot(adj[(size_t)row * N_ + key] != 0);
    if (lane == 0) P[(size_t)row * 32 + chunk * 4 + wave] = m;
}

// ---------------------------------------------------------------------------
// Kernel 1: QKV projection via MFMA, fused fp32->f16 convert.
// Q,K -> [bh][n][dh] f16 (via LDS roundtrip); V -> Vt [bh][dh][n] f16
// stored DIRECTLY from MFMA C-regs (C rows quad*4+r are contiguous n).
// ---------------------------------------------------------------------------
__global__ __launch_bounds__(256) void proj_mfma(
    const float* __restrict__ x,
    const float* __restrict__ Wq, const float* __restrict__ Wk, const float* __restrict__ Wv,
    const float* __restrict__ bq, const float* __restrict__ bk, const float* __restrict__ bv,
    f16* __restrict__ Qh, f16* __restrict__ Kh, f16* __restrict__ Vt)
{
    const int which = blockIdx.z;
    const float* W    = which == 0 ? Wq : which == 1 ? Wk : Wv;
    const float* bias = which == 0 ? bq : which == 1 ? bk : bv;

    const int r0 = blockIdx.x * 64;
    const int hy = blockIdx.y;
    const int c0 = hy * 64;
    const int tid  = threadIdx.x;
    const int wave = tid >> 6, lane = tid & 63;
    const int quad = lane >> 4, l16 = lane & 15;
    const int row = tid >> 2, seg = tid & 3;

    __shared__ f16 xs[64 * SP];
    __shared__ f16 wsm[64 * SP];

    floatx4 zz = {0.f, 0.f, 0.f, 0.f};
    floatx4 acc[4] = {zz, zz, zz, zz};

    for (int f0 = 0; f0 < F_; f0 += 64) {
        const float* xsrc = x + (size_t)(r0 + row) * F_ + f0 + seg * 16;
        const float* wsrc = W + (size_t)(c0 + row) * F_ + f0 + seg * 16;
        float4 xa0 = *(const float4*)(xsrc + 0), xa1 = *(const float4*)(xsrc + 4);
        float4 xa2 = *(const float4*)(xsrc + 8), xa3 = *(const float4*)(xsrc + 12);
        float4 wa0 = *(const float4*)(wsrc + 0), wa1 = *(const float4*)(wsrc + 4);
        float4 wa2 = *(const float4*)(wsrc + 8), wa3 = *(const float4*)(wsrc + 12);
        __syncthreads();
        *(half8*)&xs[row * SP + seg * 16]      = cvt8(xa0, xa1);
        *(half8*)&xs[row * SP + seg * 16 + 8]  = cvt8(xa2, xa3);
        *(half8*)&wsm[row * SP + seg * 16]     = cvt8(wa0, wa1);
        *(half8*)&wsm[row * SP + seg * 16 + 8] = cvt8(wa2, wa3);
        __syncthreads();
#pragma unroll
        for (int s = 0; s < 2; s++) {
            half8 af = *(const half8*)&xs[(wave * 16 + l16) * SP + s * 32 + quad * 8];
#pragma unroll
            for (int ot = 0; ot < 4; ot++) {
                half8 bf = *(const half8*)&wsm[(ot * 16 + l16) * SP + s * 32 + quad * 8];
                acc[ot] = __builtin_amdgcn_mfma_f32_16x16x32_f16(af, bf, acc[ot], 0, 0, 0);
            }
        }
    }

    const int bb = r0 >> 11, nn0 = r0 & (N_ - 1);

    if (which == 2) {
        // direct transposed store: D col(l16)=o(dh), rows quad*4+r = contiguous n
#pragma unroll
        for (int ot = 0; ot < 4; ot++) {
            const float bv_ = bias[c0 + ot * 16 + l16];
            half4v h4;
#pragma unroll
            for (int r = 0; r < 4; r++) h4[r] = (f16)(acc[ot][r] + bv_);
            *(half4v*)(Vt + (((size_t)bb * H_ + hy) * DH + ot * 16 + l16) * N_
                          + nn0 + wave * 16 + quad * 4) = h4;
        }
    } else {
        f16* dst = which == 0 ? Qh : Kh;
        __syncthreads();
        f16* outb = xs;   // reuse
#pragma unroll
        for (int ot = 0; ot < 4; ot++) {
            const float bv_ = bias[c0 + ot * 16 + l16];
#pragma unroll
            for (int r = 0; r < 4; r++)
                outb[(wave * 16 + quad * 4 + r) * SP + ot * 16 + l16] = (f16)(acc[ot][r] + bv_);
        }
        __syncthreads();
        f16* g = dst + (((size_t)bb * H_ + hy) * N_ + nn0 + row) * DH + seg * 16;
        *(float4*)(g)     = *(const float4*)&outb[row * SP + seg * 16];
        *(float4*)(g + 8) = *(const float4*)&outb[row * SP + seg * 16 + 8];
    }
}

// ---------------------------------------------------------------------------
// Kernel 2: MFMA chunked attention, chunk-split x4.
// blockIdx.x = split*32 + ntile; each block: 64 q, 2 key chunks.
// LDS: Q slab reused as per-wave P slab after fragment extraction (27.6 KB).
// Mask from packed bits (1 uint64 per 64-key tile per lane).
// Output: f16 partial CTXP[split][b*N+q][F].
// ---------------------------------------------------------------------------
__global__ __launch_bounds__(256) void attn_mfma(
    const f16* __restrict__ Qh, const f16* __restrict__ Kh,
    const f16* __restrict__ Vt, const u64* __restrict__ Padj,
    f16* __restrict__ CTXP)
{
    const int nt = blockIdx.x & 31;
    const int sp = blockIdx.x >> 5;        // split 0..3
    const int qb = nt * 64;
    const int h  = blockIdx.y;
    const int b  = blockIdx.z;
    const int bh = b * H_ + h;
    const int tid  = threadIdx.x;
    const int wave = tid >> 6, lane = tid & 63;
    const int quad = lane >> 4, l16 = lane & 15;
    const int row = tid >> 2, seg = tid & 3;

    __shared__ f16 QPs[64 * SP];   // Q stage, then per-wave P slabs
    __shared__ f16 Ks[64 * SP];
    __shared__ f16 Vs[64 * SP];    // [d][key]

    {   // stage Q tile [q][dh]
        const f16* src = Qh + ((size_t)bh * N_ + qb + row) * DH + seg * 16;
        *(float4*)&QPs[row * SP + seg * 16]     = *(const float4*)(src);
        *(float4*)&QPs[row * SP + seg * 16 + 8] = *(const float4*)(src + 8);
    }
    __syncthreads();
    // Q B-fragments: wave reads only its own 16 rows -> safe to reuse as Ps
    const half8 qf0 = *(const half8*)&QPs[(wave * 16 + l16) * SP + quad * 8];
    const half8 qf1 = *(const half8*)&QPs[(wave * 16 + l16) * SP + 32 + quad * 8];
    f16* Ps = QPs + wave * 16 * SP;   // wave-private 16 x SP

    const int qglob = qb + wave * 16 + l16;
    const u64* arow = Padj + (size_t)qglob * 32;

    floatx4 zz = {0.f, 0.f, 0.f, 0.f};
    floatx4 ctx_tot[4] = {zz, zz, zz, zz};

    for (int ci = 0; ci < 2; ci++) {
        const int c = sp * 2 + ci;
        floatx4 ctx_ch[4] = {zz, zz, zz, zz};
        float rs_ch = 0.f;

        for (int kt = 0; kt < 4; kt++) {
            const int k0 = c * 256 + kt * 64;
            const f16* ksrc = Kh + ((size_t)bh * N_ + k0 + row) * DH + seg * 16;
            const f16* vsrc = Vt + ((size_t)bh * DH + row) * N_ + k0 + seg * 16;
            float4 ka0 = *(const float4*)(ksrc), ka1 = *(const float4*)(ksrc + 8);
            float4 va0 = *(const float4*)(vsrc), va1 = *(const float4*)(vsrc + 8);
            __syncthreads();
            *(float4*)&Ks[row * SP + seg * 16]     = ka0;
            *(float4*)&Ks[row * SP + seg * 16 + 8] = ka1;
            *(float4*)&Vs[row * SP + seg * 16]     = va0;
            *(float4*)&Vs[row * SP + seg * 16 + 8] = va1;
            __syncthreads();

            const u64 aw = arow[k0 >> 6];
            float rs = 0.f;
#pragma unroll
            for (int m = 0; m < 4; m++) {
                floatx4 sacc = zz;
                half8 a0 = *(const half8*)&Ks[(m * 16 + l16) * SP + quad * 8];
                half8 a1 = *(const half8*)&Ks[(m * 16 + l16) * SP + 32 + quad * 8];
                sacc = __builtin_amdgcn_mfma_f32_16x16x32_f16(a0, qf0, sacc, 0, 0, 0);
                sacc = __builtin_amdgcn_mfma_f32_16x16x32_f16(a1, qf1, sacc, 0, 0, 0);
                const unsigned int nib = (unsigned int)(aw >> (m * 16 + quad * 4)) & 0xFu;
                half4v pv;
#pragma unroll
                for (int r = 0; r < 4; r++) {
                    float sv = sacc[r] * 0.125f;
                    sv = fminf(fmaxf(sv, -10.f), 10.f);
                    sv = ((nib >> r) & 1u) ? sv : -10.f;
                    const float ev = __expf(sv);
                    rs += ev;
                    pv[r] = (f16)ev;
                }
                *(half4v*)&Ps[l16 * SP + m * 16 + quad * 4] = pv;
            }
            rs += __shfl_xor(rs, 16);
            rs += __shfl_xor(rs, 32);
            rs_ch += rs;

            const half8 p0 = *(const half8*)&Ps[l16 * SP + quad * 8];
            const half8 p1 = *(const half8*)&Ps[l16 * SP + 32 + quad * 8];
#pragma unroll
            for (int m = 0; m < 4; m++) {
                half8 va = *(const half8*)&Vs[(m * 16 + l16) * SP + quad * 8];
                half8 vb = *(const half8*)&Vs[(m * 16 + l16) * SP + 32 + quad * 8];
                ctx_ch[m] = __builtin_amdgcn_mfma_f32_16x16x32_f16(va, p0, ctx_ch[m], 0, 0, 0);
                ctx_ch[m] = __builtin_amdgcn_mfma_f32_16x16x32_f16(vb, p1, ctx_ch[m], 0, 0, 0);
            }
        }

        const float inv = 1.0f / rs_ch;
#pragma unroll
        for (int m = 0; m < 4; m++)
#pragma unroll
            for (int r = 0; r < 4; r++)
                ctx_tot[m][r] += ctx_ch[m][r] * inv;
    }

    // store f16 partial: col=q (lane), rows d = m*16+quad*4+r contiguous
    f16* dst = CTXP + (((size_t)sp * B_ + b) * N_ + qglob) * F_ + h * DH;
#pragma unroll
    for (int m = 0; m < 4; m++) {
        half4v h4;
#pragma unroll
        for (int r = 0; r < 4; r++) h4[r] = (f16)ctx_tot[m][r];
        *(half4v*)&dst[m * 16 + quad * 4] = h4;
    }
}

// ---------------------------------------------------------------------------
// Kernel 3: sum 4 f16 partials -> fp32 CTX.
// ---------------------------------------------------------------------------
__global__ __launch_bounds__(256) void sum_ctx(
    const f16* __restrict__ CTXP, float* __restrict__ CTX)
{
    const size_t S = (size_t)BN * F_;
    const size_t i = ((size_t)blockIdx.x * 256 + threadIdx.x) * 8;
    half8 a0 = *(const half8*)(CTXP + i);
    half8 a1 = *(const half8*)(CTXP + S + i);
    half8 a2 = *(const half8*)(CTXP + 2 * S + i);
    half8 a3 = *(const half8*)(CTXP + 3 * S + i);
    float4 o0, o1;
    o0.x = (float)a0[0] + (float)a1[0] + (float)a2[0] + (float)a3[0];
    o0.y = (float)a0[1] + (float)a1[1] + (float)a2[1] + (float)a3[1];
    o0.z = (float)a0[2] + (float)a1[2] + (float)a2[2] + (float)a3[2];
    o0.w = (float)a0[3] + (float)a1[3] + (float)a2[3] + (float)a3[3];
    o1.x = (float)a0[4] + (float)a1[4] + (float)a2[4] + (float)a3[4];
    o1.y = (float)a0[5] + (float)a1[5] + (float)a2[5] + (float)a3[5];
    o1.z = (float)a0[6] + (float)a1[6] + (float)a2[6] + (float)a3[6];
    o1.w = (float)a0[7] + (float)a1[7] + (float)a2[7] + (float)a3[7];
    *(float4*)(CTX + i)     = o0;
    *(float4*)(CTX + i + 4) = o1;
}

// ---------------------------------------------------------------------------
// Kernel 4a: transpose Wo (256x256 fp32) for the coalesced epilogue.
// ---------------------------------------------------------------------------
__global__ __launch_bounds__(256) void transpose_wo(
    const float* __restrict__ Wo, float* __restrict__ WoT)
{
    const int idx = blockIdx.x * 256 + threadIdx.x;
    const int f = idx >> 8;
    const int o = idx & 255;
    WoT[(size_t)f * F_ + o] = Wo[(size_t)o * F_ + f];
}

// ---------------------------------------------------------------------------
// Kernel 4b: out = LN(ctx @ Wo^T + bo + x), fp32.  Block = 4 rows x 256 cols.
// ---------------------------------------------------------------------------
__global__ __launch_bounds__(256) void out_ln_kernel(
    const float* __restrict__ CTX, const float* __restrict__ x,
    const float* __restrict__ WoT, const float* __restrict__ bo,
    const float* __restrict__ gamma, const float* __restrict__ beta,
    float* __restrict__ out)
{
    const int n0 = blockIdx.x * 4;
    const int o  = threadIdx.x;

    float acc[4] = {0.f, 0.f, 0.f, 0.f};
    for (int f = 0; f < F_; f += 4) {
        const float w0 = WoT[(size_t)(f + 0) * F_ + o];
        const float w1 = WoT[(size_t)(f + 1) * F_ + o];
        const float w2 = WoT[(size_t)(f + 2) * F_ + o];
        const float w3 = WoT[(size_t)(f + 3) * F_ + o];
#pragma unroll
        for (int r = 0; r < 4; r++) {
            float4 c4 = *(const float4*)(CTX + (size_t)(n0 + r) * F_ + f);
            acc[r] += c4.x * w0 + c4.y * w1 + c4.z * w2 + c4.w * w3;
        }
    }

    float ov[4];
#pragma unroll
    for (int r = 0; r < 4; r++)
        ov[r] = acc[r] + bo[o] + x[(size_t)(n0 + r) * F_ + o];

    __shared__ float psum[4][4], psq[4][4];
    const int wave = o >> 6, lane = o & 63;
#pragma unroll
    for (int r = 0; r < 4; r++) {
        float sv = ov[r], qv = ov[r] * ov[r];
#pragma unroll
        for (int off = 1; off < 64; off <<= 1) {
            sv += __shfl_xor(sv, off);
            qv += __shfl_xor(qv, off);
        }
        if (lane == 0) { psum[wave][r] = sv; psq[wave][r] = qv; }
    }
    __syncthreads();
#pragma unroll
    for (int r = 0; r < 4; r++) {
        const float S  = (psum[0][r] + psum[1][r]) + (psum[2][r] + psum[3][r]);
        const float Q2 = (psq[0][r] + psq[1][r]) + (psq[2][r] + psq[3][r]);
        const float mu  = S * (1.0f / F_);
        const float var = Q2 * (1.0f / F_) - mu * mu;
        const float inv = rsqrtf(var + 1e-5f);
        out[(size_t)(n0 + r) * F_ + o] = (ov[r] - mu) * inv * gamma[o] + beta[o];
    }
}

// ---------------------------------------------------------------------------
extern "C" void kernel_launch(void* const* d_in, const int* in_sizes, int n_in,
                              void* d_out, int out_size, void* d_ws, size_t ws_size,
                              hipStream_t stream)
{
    const float* x     = (const float*)d_in[0];
    const int*   adj   = (const int*)  d_in[1];
    const float* Wq    = (const float*)d_in[2];
    const float* bq    = (const float*)d_in[3];
    const float* Wk    = (const float*)d_in[4];
    const float* bk    = (const float*)d_in[5];
    const float* Wv    = (const float*)d_in[6];
    const float* bv    = (const float*)d_in[7];
    const float* Wo    = (const float*)d_in[8];
    const float* bo    = (const float*)d_in[9];
    const float* gamma = (const float*)d_in[10];
    const float* beta  = (const float*)d_in[11];
    float* out = (float*)d_out;

    float* ws = (float*)d_ws;
    float* WoT  = ws;                               //    65,536 fl
    f16*   CTXP = (f16*)(ws + 65536);               // 8M halves = 4,194,304 fl
    f16*   Qh   = (f16*)(ws + 4259840);             // 2M halves = 1,048,576 fl
    f16*   Kh   = (f16*)(ws + 5308416);
    f16*   Vt   = (f16*)(ws + 6356992);
    u64*   Padj = (u64*)(ws + 7405568);             //   131,072 fl (512 KB)
    float* CTX  = (float*)Qh;                       // overlay: Qh+Kh dead after attn

    hipLaunchKernelGGL(pack_adj, dim3(N_ * 8), dim3(256), 0, stream, adj, Padj);
    hipLaunchKernelGGL(proj_mfma, dim3(BN / 64, H_, 3), dim3(256), 0, stream,
                       x, Wq, Wk, Wv, bq, bk, bv, Qh, Kh, Vt);
    hipLaunchKernelGGL(transpose_wo, dim3((F_ * F_) / 256), dim3(256), 0, stream,
                       Wo, WoT);
    hipLaunchKernelGGL(attn_mfma, dim3(128, H_, B_), dim3(256), 0, stream,
                       Qh, Kh, Vt, Padj, CTXP);
    hipLaunchKernelGGL(sum_ctx, dim3(1024), dim3(256), 0, stream, CTXP, CTX);
    hipLaunchKernelGGL(out_ln_kernel, dim3(BN / 4), dim3(256), 0, stream,
                       CTX, x, WoT, bo, gamma, beta, out);
}